// Round 1
// baseline (283.096 us; speedup 1.0000x reference)
//
#include <hip/hip_runtime.h>
#include <math.h>

#define C_ 100
#define K_ 8
#define D_ 64
#define B_ 2048
#define BT 128

// ---------------- kernel 1: invert unit-lower-triangular L per (c,k) ----------------
// Ac[j][m] holds A[m][j]  (thread j owns column j of A = row j of Ac -> no cross-thread
// dependencies inside the substitution loop, so no barriers needed there).
__global__ __launch_bounds__(64) void k_invert(const float* __restrict__ L_g,
                                               const float* __restrict__ loc_g,
                                               float* __restrict__ AT_g,
                                               float* __restrict__ v_g,
                                               float* __restrict__ ld_g) {
    const int ck = blockIdx.x;
    const int j = threadIdx.x;
    __shared__ float Ls[D_][D_ + 1];
    __shared__ float Ac[D_][D_ + 1];
    __shared__ float mus[D_];

    const float* Lsrc = L_g + (size_t)ck * D_ * D_;
    for (int idx = j; idx < D_ * D_; idx += 64)
        Ls[idx >> 6][idx & 63] = Lsrc[idx];
    mus[j] = loc_g[ck * D_ + j];
    for (int m = 0; m < D_; ++m) Ac[j][m] = (m == j) ? 1.0f : 0.0f;
    __syncthreads();

    if (j == 0) {
        float s = 0.f;
        for (int d = 0; d < D_; ++d) s += logf(fabsf(Ls[d][d]));
        ld_g[ck] = s;
    }

    // forward substitution: A[i][j] = -sum_{m<i} L[i][m] * A[m][j]  (for j < i)
    for (int i = 1; i < D_; ++i) {
        float acc = 0.f;
        for (int m = 0; m < i; ++m) acc += Ls[i][m] * Ac[j][m];
        if (j < i) Ac[j][i] = -acc;
    }
    __syncthreads();

    // v[d] = sum_j A[d][j] * mu[j];  A[d][jj] = Ac[jj][d]
    float accv = 0.f;
    for (int jj = 0; jj < D_; ++jj) accv += Ac[jj][j] * mus[jj];
    v_g[ck * D_ + j] = accv;

    float* ATo = AT_g + (size_t)ck * D_ * D_;
    for (int idx = j; idx < D_ * D_; idx += 64)
        ATo[idx] = Ac[idx >> 6][idx & 63];   // AT[jrow][d] = A[d][jrow]
}

// ---------------- kernel 2: per-(c,k) offsets = mix - logdet - 0.5*D*log(2pi) --------
__global__ void k_offs(const float* __restrict__ ml, const float* __restrict__ ld,
                       float* __restrict__ off) {
    const int c = threadIdx.x;
    if (c >= C_) return;
    float v[K_];
    float m = -INFINITY;
    for (int k = 0; k < K_; ++k) { v[k] = ml[c * K_ + k]; m = fmaxf(m, v[k]); }
    float s = 0.f;
    for (int k = 0; k < K_; ++k) s += expf(v[k] - m);
    const float lse = m + logf(s);
    for (int k = 0; k < K_; ++k)
        off[c * K_ + k] = v[k] - lse - 58.8120661251f - ld[c * K_ + k];
}

// ---------------- kernel 3: fused GEMM + quad + logsumexp over K ---------------------
// block: 256 threads, handles one class c and a 128-batch tile; loops k=0..7.
__global__ __launch_bounds__(256) void k_main(const float* __restrict__ rep,
                                              const float* __restrict__ AT_g,
                                              const float* __restrict__ v_g,
                                              const float* __restrict__ off_g,
                                              float* __restrict__ clp_g) {
    const int c = blockIdx.y;
    const int b0 = blockIdx.x * BT;
    const int tid = threadIdx.x;

    __shared__ float Xs[D_][BT + 4];   // Xs[j][b]
    __shared__ float As[D_][D_ + 4];   // As[j][d] = A[d][j]
    __shared__ float red[16][BT];
    __shared__ float qk[BT][K_ + 1];
    __shared__ float vs[D_];
    __shared__ float offs[K_];

    // stage X tile (transposed)
    for (int idx = tid; idx < BT * (D_ / 4); idx += 256) {
        const int bb = idx >> 4, q = idx & 15;
        const float4 x4 = reinterpret_cast<const float4*>(rep + (size_t)(b0 + bb) * D_)[q];
        Xs[4 * q + 0][bb] = x4.x;
        Xs[4 * q + 1][bb] = x4.y;
        Xs[4 * q + 2][bb] = x4.z;
        Xs[4 * q + 3][bb] = x4.w;
    }
    if (tid < K_) offs[tid] = off_g[c * K_ + tid];

    const int dg = tid >> 4;                    // 0..15 -> d0 = 4*dg
    const int bg = tid & 15;                    // 0..15 -> b in {4bg..}, {64+4bg..}
    const int d0 = dg * 4;
    const int jmax = ((tid >> 6) + 1) << 4;     // wave-uniform triangular bound

    for (int k = 0; k < K_; ++k) {
        __syncthreads();   // previous iteration done with As/vs/red (and X staged, 1st iter)
        const float* Asrc = AT_g + ((size_t)(c * K_ + k)) * D_ * D_;
        for (int idx = tid; idx < D_ * D_ / 4; idx += 256) {
            const int jj = idx >> 4, q = idx & 15;
            *reinterpret_cast<float4*>(&As[jj][4 * q]) =
                reinterpret_cast<const float4*>(Asrc)[idx];
        }
        if (tid < D_) vs[tid] = v_g[(c * K_ + k) * D_ + tid];
        __syncthreads();

        float acc[8][4];
#pragma unroll
        for (int bi = 0; bi < 8; ++bi)
#pragma unroll
            for (int di = 0; di < 4; ++di) acc[bi][di] = 0.f;

#pragma unroll 8
        for (int jj = 0; jj < jmax; ++jj) {
            const float4 a4 = *reinterpret_cast<const float4*>(&As[jj][d0]);
            const float4 xa = *reinterpret_cast<const float4*>(&Xs[jj][4 * bg]);
            const float4 xb = *reinterpret_cast<const float4*>(&Xs[jj][64 + 4 * bg]);
            const float av[4] = {a4.x, a4.y, a4.z, a4.w};
            const float xv[8] = {xa.x, xa.y, xa.z, xa.w, xb.x, xb.y, xb.z, xb.w};
#pragma unroll
            for (int bi = 0; bi < 8; ++bi)
#pragma unroll
                for (int di = 0; di < 4; ++di)
                    acc[bi][di] = fmaf(xv[bi], av[di], acc[bi][di]);
        }

        // epilogue: partial quad per (b, d-group)
#pragma unroll
        for (int bi = 0; bi < 8; ++bi) {
            const int bb = (bi < 4) ? (4 * bg + bi) : (64 + 4 * bg + (bi - 4));
            float s = 0.f;
#pragma unroll
            for (int di = 0; di < 4; ++di) {
                const float z = acc[bi][di] - vs[d0 + di];
                s += z * z;
            }
            red[dg][bb] = s;
        }
        __syncthreads();
        if (tid < BT) {
            float q = 0.f;
#pragma unroll
            for (int g = 0; g < 16; ++g) q += red[g][tid];
            qk[tid][k] = q;
        }
    }
    __syncthreads();

    if (tid < BT) {
        float lp[K_];
        float m = -INFINITY;
#pragma unroll
        for (int k = 0; k < K_; ++k) {
            lp[k] = offs[k] - 0.5f * qk[tid][k];
            m = fmaxf(m, lp[k]);
        }
        float s = 0.f;
#pragma unroll
        for (int k = 0; k < K_; ++k) s += expf(lp[k] - m);
        clp_g[(size_t)(b0 + tid) * C_ + c] = m + logf(s);
    }
}

// ---------------- kernel 4: log_softmax over C per batch row -------------------------
__global__ __launch_bounds__(256) void k_final(const float* __restrict__ clp,
                                               float* __restrict__ out) {
    const int wave = threadIdx.x >> 6;
    const int lane = threadIdx.x & 63;
    const int b = blockIdx.x * 4 + wave;
    const float* row = clp + (size_t)b * C_;
    const float x0 = row[lane];                                    // lane < 64 <= C
    const float x1 = (lane < C_ - 64) ? row[64 + lane] : -INFINITY;
    float m = fmaxf(x0, x1);
    for (int o = 32; o > 0; o >>= 1) m = fmaxf(m, __shfl_xor(m, o, 64));
    float s = expf(x0 - m) + ((lane < C_ - 64) ? expf(x1 - m) : 0.f);
    for (int o = 32; o > 0; o >>= 1) s += __shfl_xor(s, o, 64);
    const float L = m + logf(s);
    out[(size_t)b * C_ + lane] = x0 - L;
    if (lane < C_ - 64) out[(size_t)b * C_ + 64 + lane] = x1 - L;
}

extern "C" void kernel_launch(void* const* d_in, const int* in_sizes, int n_in,
                              void* d_out, int out_size, void* d_ws, size_t ws_size,
                              hipStream_t stream) {
    const float* rep = (const float*)d_in[0];        // [B, D]
    const float* ml  = (const float*)d_in[1];        // [C, K]
    const float* loc = (const float*)d_in[2];        // [C, K, D]
    const float* st  = (const float*)d_in[3];        // [C, K, D, D]
    float* out = (float*)d_out;                      // [B, C]

    float* ws = (float*)d_ws;
    float* AT  = ws;                                  // 800*4096 = 3,276,800
    float* v   = AT + (size_t)C_ * K_ * D_ * D_;      // 51,200
    float* ld  = v + (size_t)C_ * K_ * D_;            // 800
    float* off = ld + (size_t)C_ * K_;                // 800
    float* clp = off + (size_t)C_ * K_;               // 204,800  (total ~14.2 MB)

    k_invert<<<dim3(C_ * K_), dim3(64), 0, stream>>>(st, loc, AT, v, ld);
    k_offs<<<dim3(1), dim3(128), 0, stream>>>(ml, ld, off);
    k_main<<<dim3(B_ / BT, C_), dim3(256), 0, stream>>>(rep, AT, v, off, clp);
    k_final<<<dim3(B_ / 4), dim3(256), 0, stream>>>(clp, out);
}

// Round 2
// 159.077 us; speedup vs baseline: 1.7796x; 1.7796x over previous
//
#include <hip/hip_runtime.h>
#include <math.h>

#define C_ 100
#define K_ 8
#define D_ 64
#define B_ 2048

using f16x8 = __attribute__((ext_vector_type(8))) _Float16;
using f32x4 = __attribute__((ext_vector_type(4))) float;

// DPP-based cross-lane add within each 16-lane group (order: xor1, xor2,
// then half_mirror(≡xor4 after xor1/2 summed) and mirror(≡xor8)).
template <int CTRL>
__device__ __forceinline__ float dpp_xadd(float x) {
    int v = __builtin_amdgcn_update_dpp(0, __float_as_int(x), CTRL, 0xf, 0xf, true);
    return x + __int_as_float(v);
}
__device__ __forceinline__ float sum16(float x) {
    x = dpp_xadd<0xB1>(x);   // quad_perm [1,0,3,2]  : xor 1
    x = dpp_xadd<0x4E>(x);   // quad_perm [2,3,0,1]  : xor 2
    x = dpp_xadd<0x141>(x);  // row_half_mirror      : xor 7 ≡ xor 4
    x = dpp_xadd<0x140>(x);  // row_mirror           : xor 15 ≡ xor 8
    return x;
}

// ---------------- kernel 1: invert unit-lower-triangular L per (c,k) ----------------
// Also: casts X -> fp16, emits A in MFMA B-fragment order (fp16), v = A_f16 * mu (fp32).
__global__ __launch_bounds__(64) void k_invert(const float* __restrict__ L_g,
                                               const float* __restrict__ rep,
                                               const float* __restrict__ loc_g,
                                               f16x8* __restrict__ ATf,
                                               _Float16* __restrict__ Xh,
                                               float* __restrict__ v_g,
                                               float* __restrict__ ld_g) {
    const int ck = blockIdx.x;
    const int j = threadIdx.x;
    __shared__ float Ls[D_][D_ + 1];
    __shared__ float Ac[D_][D_ + 1];   // Ac[j][m] = A[m][j] (thread j owns column j)
    __shared__ float mus[D_];

    // independent work: cast X to fp16 (strided across all 800 blocks)
    for (int idx = ck * 64 + j; idx < B_ * D_; idx += C_ * K_ * 64)
        Xh[idx] = (_Float16)rep[idx];

    const float* Lsrc = L_g + (size_t)ck * D_ * D_;
    for (int idx = j; idx < D_ * D_; idx += 64)
        Ls[idx >> 6][idx & 63] = Lsrc[idx];
    mus[j] = loc_g[ck * D_ + j];
    for (int m = 0; m < D_; ++m) Ac[j][m] = (m == j) ? 1.0f : 0.0f;
    __syncthreads();

    if (j == 0) {
        float s = 0.f;
        for (int d = 0; d < D_; ++d) s += logf(fabsf(Ls[d][d]));
        ld_g[ck] = s;   // == 0 for unit diagonal, kept for generality
    }

    // forward substitution: A[i][j] = -sum_{m<i} L[i][m] * A[m][j]  (unit diagonal)
    for (int i = 1; i < D_; ++i) {
        float acc = 0.f;
        for (int m = 0; m < i; ++m) acc += Ls[i][m] * Ac[j][m];
        if (j < i) Ac[j][i] = -acc;
    }
    __syncthreads();

    // v[d] = sum_j f16(A[d][j]) * mu[j]  (rounded A for error cancellation)
    float accv = 0.f;
    for (int jj = 0; jj < D_; ++jj)
        accv += (float)(_Float16)Ac[jj][j] * mus[jj];
    v_g[ck * D_ + j] = accv;

    // emit B-fragments: frag (dt,ks), lane j, elem s  <->  B[k][n] with
    // n = dt*16 + (j&15), k(global j-dim) = ks*32 + (j>>4)*8 + s ; value A[n][k]
    const int q8 = (j >> 4) * 8, cl = j & 15;
    for (int dt = 0; dt < 4; ++dt)
        for (int ks = 0; ks < 2; ++ks) {
            f16x8 t;
#pragma unroll
            for (int s = 0; s < 8; ++s)
                t[s] = (_Float16)Ac[ks * 32 + q8 + s][dt * 16 + cl];
            ATf[(size_t)ck * 512 + (dt * 2 + ks) * 64 + j] = t;
        }
}

// ---------------- kernel 2: per-(c,k) offsets = mix - logdet - 0.5*D*log(2pi) --------
__global__ void k_offs(const float* __restrict__ ml, const float* __restrict__ ld,
                       float* __restrict__ off) {
    const int c = threadIdx.x;
    if (c >= C_) return;
    float v[K_];
    float m = -INFINITY;
    for (int k = 0; k < K_; ++k) { v[k] = ml[c * K_ + k]; m = fmaxf(m, v[k]); }
    float s = 0.f;
    for (int k = 0; k < K_; ++k) s += expf(v[k] - m);
    const float lse = m + logf(s);
    for (int k = 0; k < K_; ++k)
        off[c * K_ + k] = v[k] - lse - 58.8120661251f - ld[c * K_ + k];
}

// ---------------- kernel 3: MFMA GEMM + quad + online logsumexp over K ---------------
// block: 256 thr (4 waves) = one class c x 128 b-rows; wave handles 32 b x 64 d.
// No LDS at all.
__global__ __launch_bounds__(256, 4) void k_main(const _Float16* __restrict__ Xh,
                                                 const f16x8* __restrict__ ATf,
                                                 const float* __restrict__ v_g,
                                                 const float* __restrict__ off_g,
                                                 float* __restrict__ clp_g) {
    const int c = blockIdx.y;
    const int b0 = blockIdx.x * 128;
    const int wave = threadIdx.x >> 6;
    const int lane = threadIdx.x & 63;
    const int col = lane & 15;    // A-op row m (b), B-op col n (d), C/D col
    const int quad = lane >> 4;   // k-dim chunk selector / C/D row group
    const int bw = b0 + wave * 32;

    // X A-fragments, loaded once: A[m][k]: m=col, k = ks*32 + quad*8 + s
    f16x8 Xf[2][2];
#pragma unroll
    for (int bt = 0; bt < 2; ++bt)
#pragma unroll
        for (int ks = 0; ks < 2; ++ks)
            Xf[bt][ks] = *reinterpret_cast<const f16x8*>(
                Xh + (size_t)(bw + bt * 16 + col) * D_ + ks * 32 + quad * 8);

    float m_run[2][4], s_run[2][4];
#pragma unroll
    for (int bt = 0; bt < 2; ++bt)
#pragma unroll
        for (int r = 0; r < 4; ++r) { m_run[bt][r] = -INFINITY; s_run[bt][r] = 0.f; }

    const f32x4 zero = {0.f, 0.f, 0.f, 0.f};

    for (int k = 0; k < K_; ++k) {
        const int ck = c * K_ + k;
        const f16x8* Bb = ATf + (size_t)ck * 512;
        f16x8 Bf[4][2];
#pragma unroll
        for (int dt = 0; dt < 4; ++dt)
#pragma unroll
            for (int ks = 0; ks < 2; ++ks)
                Bf[dt][ks] = Bb[(dt * 2 + ks) * 64 + lane];
        float vv[4];
#pragma unroll
        for (int dt = 0; dt < 4; ++dt)
            vv[dt] = v_g[(size_t)ck * D_ + dt * 16 + col];
        const float offk = off_g[ck];

        f32x4 acc[2][4];
#pragma unroll
        for (int bt = 0; bt < 2; ++bt)
#pragma unroll
            for (int dt = 0; dt < 4; ++dt) {
                acc[bt][dt] = __builtin_amdgcn_mfma_f32_16x16x32_f16(
                    Xf[bt][0], Bf[dt][0], zero, 0, 0, 0);
                acc[bt][dt] = __builtin_amdgcn_mfma_f32_16x16x32_f16(
                    Xf[bt][1], Bf[dt][1], acc[bt][dt], 0, 0, 0);
            }

        // quad[b] partials: per lane sum over its 4 d's, then sum across 16 cols
#pragma unroll
        for (int bt = 0; bt < 2; ++bt) {
            float p[4];
#pragma unroll
            for (int r = 0; r < 4; ++r) {
                float s = 0.f;
#pragma unroll
                for (int dt = 0; dt < 4; ++dt) {
                    const float z = acc[bt][dt][r] - vv[dt];
                    s = fmaf(z, z, s);
                }
                p[r] = s;
            }
#pragma unroll
            for (int r = 0; r < 4; ++r) p[r] = sum16(p[r]);
            // online logsumexp over k
#pragma unroll
            for (int r = 0; r < 4; ++r) {
                const float lp = fmaf(-0.5f, p[r], offk);
                const float nm = fmaxf(m_run[bt][r], lp);
                s_run[bt][r] = s_run[bt][r] * expf(m_run[bt][r] - nm) + expf(lp - nm);
                m_run[bt][r] = nm;
            }
        }
    }

    if (col == 0) {
#pragma unroll
        for (int bt = 0; bt < 2; ++bt)
#pragma unroll
            for (int r = 0; r < 4; ++r) {
                const int b = bw + bt * 16 + quad * 4 + r;
                clp_g[(size_t)b * C_ + c] = m_run[bt][r] + logf(s_run[bt][r]);
            }
    }
}

// ---------------- kernel 4: log_softmax over C per batch row -------------------------
__global__ __launch_bounds__(256) void k_final(const float* __restrict__ clp,
                                               float* __restrict__ out) {
    const int wave = threadIdx.x >> 6;
    const int lane = threadIdx.x & 63;
    const int b = blockIdx.x * 4 + wave;
    const float* row = clp + (size_t)b * C_;
    const float x0 = row[lane];
    const float x1 = (lane < C_ - 64) ? row[64 + lane] : -INFINITY;
    float m = fmaxf(x0, x1);
    for (int o = 32; o > 0; o >>= 1) m = fmaxf(m, __shfl_xor(m, o, 64));
    float s = expf(x0 - m) + ((lane < C_ - 64) ? expf(x1 - m) : 0.f);
    for (int o = 32; o > 0; o >>= 1) s += __shfl_xor(s, o, 64);
    const float L = m + logf(s);
    out[(size_t)b * C_ + lane] = x0 - L;
    if (lane < C_ - 64) out[(size_t)b * C_ + 64 + lane] = x1 - L;
}

extern "C" void kernel_launch(void* const* d_in, const int* in_sizes, int n_in,
                              void* d_out, int out_size, void* d_ws, size_t ws_size,
                              hipStream_t stream) {
    const float* rep = (const float*)d_in[0];        // [B, D]
    const float* ml  = (const float*)d_in[1];        // [C, K]
    const float* loc = (const float*)d_in[2];        // [C, K, D]
    const float* st  = (const float*)d_in[3];        // [C, K, D, D]
    float* out = (float*)d_out;                      // [B, C]

    char* w = (char*)d_ws;
    f16x8*    ATf = (f16x8*)w;                        // 800*512*16 = 6,553,600 B
    _Float16* Xh  = (_Float16*)(w + 6553600);         // 262,144 B
    float*    v   = (float*)(w + 6815744);            // 204,800 B
    float*    ld  = (float*)(w + 7020544);            // 3,200 B
    float*    off = (float*)(w + 7023744);            // 3,200 B
    float*    clp = (float*)(w + 7026944);            // 819,200 B (end ~7.85 MB)

    k_invert<<<dim3(C_ * K_), dim3(64), 0, stream>>>(st, rep, loc, ATf, Xh, v, ld);
    k_offs<<<dim3(1), dim3(128), 0, stream>>>(ml, ld, off);
    k_main<<<dim3(B_ / 128, C_), dim3(256), 0, stream>>>(Xh, ATf, v, off, clp);
    k_final<<<dim3(B_ / 4), dim3(256), 0, stream>>>(clp, out);
}

// Round 3
// 117.007 us; speedup vs baseline: 2.4195x; 1.3596x over previous
//
#include <hip/hip_runtime.h>
#include <math.h>

#define C_ 100
#define K_ 8
#define D_ 64
#define B_ 2048

using f16x8 = __attribute__((ext_vector_type(8))) _Float16;
using f32x4 = __attribute__((ext_vector_type(4))) float;

// DPP-based cross-lane add within each 16-lane group.
template <int CTRL>
__device__ __forceinline__ float dpp_xadd(float x) {
    int v = __builtin_amdgcn_update_dpp(0, __float_as_int(x), CTRL, 0xf, 0xf, true);
    return x + __int_as_float(v);
}
__device__ __forceinline__ float sum16(float x) {
    x = dpp_xadd<0xB1>(x);   // quad_perm xor1
    x = dpp_xadd<0x4E>(x);   // quad_perm xor2
    x = dpp_xadd<0x141>(x);  // row_half_mirror ≡ xor4
    x = dpp_xadd<0x140>(x);  // row_mirror ≡ xor8
    return x;
}

// ---------------- kernel 1: invert unit-lower-triangular L per (c,k) ----------------
// Register-resident substitution: thread j holds column j of A in a[64] (all indices
// compile-time after full unroll). Inner loop reads only Ls rows = wave-uniform LDS
// broadcast (b128). Emits B-fragments (f16), v = A_f16*mu, logdet. Also casts X->f16.
#define LS_S 68   // Ls row stride (floats): 16B-aligned rows, staggers banks by 4/row
#define AT_S 65   // At row stride: bank (row+col)%32 -> 2-way max (free)
__global__ __launch_bounds__(64) void k_invert(const float* __restrict__ L_g,
                                               const float* __restrict__ rep,
                                               const float* __restrict__ loc_g,
                                               f16x8* __restrict__ ATf,
                                               _Float16* __restrict__ Xh,
                                               float* __restrict__ v_g,
                                               float* __restrict__ ld_g) {
    const int ck = blockIdx.x;
    const int j = threadIdx.x;
    __shared__ float Ls[D_][LS_S];
    __shared__ float At[D_][AT_S];   // At[m][j] = A[m][j]
    __shared__ float mus[D_];

    // cast X to fp16 (strided across all 800 blocks) — independent work
    for (int idx = ck * 64 + j; idx < B_ * D_; idx += C_ * K_ * 64)
        Xh[idx] = (_Float16)rep[idx];

    // stage L: scalar coalesced global loads, col-j LDS writes (2-way, free)
    const float* Lsrc = L_g + (size_t)ck * D_ * D_;
#pragma unroll
    for (int t = 0; t < D_; ++t)
        Ls[t][j] = Lsrc[t * D_ + j];
    mus[j] = loc_g[ck * D_ + j];
    __syncthreads();

    // logdet: per-lane log of own diagonal, wave-reduce
    {
        float ll = __logf(fabsf(Ls[j][j]));
        ll = sum16(ll);
        ll += __shfl_xor(ll, 16, 64);
        ll += __shfl_xor(ll, 32, 64);
        if (j == 0) ld_g[ck] = ll;
    }

    // substitution: a[i] = -(sum_{m<i} L[i][m] a[m]) / L[i][i]
    float a[D_];
    const float r0 = __builtin_amdgcn_rcpf(Ls[j][j]);
#pragma unroll
    for (int m = 0; m < D_; ++m) a[m] = (j == m) ? r0 : 0.f;

#pragma unroll
    for (int i = 1; i < D_; ++i) {
        float a0 = 0.f, a1 = 0.f, a2 = 0.f, a3 = 0.f;
#pragma unroll
        for (int m0 = 0; m0 + 3 < i; m0 += 4) {
            const float4 L4 = *reinterpret_cast<const float4*>(&Ls[i][m0]);
            a0 = fmaf(L4.x, a[m0 + 0], a0);
            a1 = fmaf(L4.y, a[m0 + 1], a1);
            a2 = fmaf(L4.z, a[m0 + 2], a2);
            a3 = fmaf(L4.w, a[m0 + 3], a3);
        }
#pragma unroll
        for (int m = i & ~3; m < i; ++m) a0 = fmaf(Ls[i][m], a[m], a0);
        const float acc = (a0 + a1) + (a2 + a3);
        const float nv = -acc * __builtin_amdgcn_rcpf(Ls[i][i]);
        a[i] = (j < i) ? nv : a[i];
    }

    // transpose through LDS for fragment packing
#pragma unroll
    for (int m = 0; m < D_; ++m) At[m][j] = a[m];
    __syncthreads();

    // pack B-fragments + compute v from the f16-rounded fragments
    const int q8 = (j >> 4) * 8, cl = j & 15;
    float vpart[4];
#pragma unroll
    for (int dt = 0; dt < 4; ++dt) {
        vpart[dt] = 0.f;
#pragma unroll
        for (int ks = 0; ks < 2; ++ks) {
            f16x8 t;
#pragma unroll
            for (int s = 0; s < 8; ++s) {
                const _Float16 h = (_Float16)At[dt * 16 + cl][ks * 32 + q8 + s];
                t[s] = h;
                vpart[dt] = fmaf((float)h, mus[ks * 32 + q8 + s], vpart[dt]);
            }
            ATf[(size_t)ck * 512 + (dt * 2 + ks) * 64 + j] = t;
        }
        vpart[dt] += __shfl_xor(vpart[dt], 16, 64);
        vpart[dt] += __shfl_xor(vpart[dt], 32, 64);
    }
    if (j < 16) {
#pragma unroll
        for (int dt = 0; dt < 4; ++dt)
            v_g[(size_t)ck * D_ + dt * 16 + j] = vpart[dt];
    }
}

// ---------------- kernel 2: MFMA GEMM + quad + online logsumexp over K ---------------
// block: 256 thr (4 waves) = one class c x 128 b-rows; wave handles 32 b x 64 d.
// Preamble folds the per-(c,k) offset computation (mix log-softmax - logdet - const).
__global__ __launch_bounds__(256, 4) void k_main(const _Float16* __restrict__ Xh,
                                                 const f16x8* __restrict__ ATf,
                                                 const float* __restrict__ v_g,
                                                 const float* __restrict__ ml,
                                                 const float* __restrict__ ld_g,
                                                 float* __restrict__ clp_g) {
    const int c = blockIdx.y;
    const int b0 = blockIdx.x * 128;
    const int tid = threadIdx.x;
    const int wave = tid >> 6;
    const int lane = tid & 63;
    const int col = lane & 15;
    const int quad = lane >> 4;
    const int bw = b0 + wave * 32;

    __shared__ float offs_s[K_];
    if (tid < K_) {
        float vals[K_];
        float mx = -INFINITY;
#pragma unroll
        for (int k = 0; k < K_; ++k) { vals[k] = ml[c * K_ + k]; mx = fmaxf(mx, vals[k]); }
        float s = 0.f;
#pragma unroll
        for (int k = 0; k < K_; ++k) s += __expf(vals[k] - mx);
        const float lse = mx + __logf(s);
        offs_s[tid] = vals[tid] - lse - 58.8120661251f - ld_g[c * K_ + tid];
    }

    f16x8 Xf[2][2];
#pragma unroll
    for (int bt = 0; bt < 2; ++bt)
#pragma unroll
        for (int ks = 0; ks < 2; ++ks)
            Xf[bt][ks] = *reinterpret_cast<const f16x8*>(
                Xh + (size_t)(bw + bt * 16 + col) * D_ + ks * 32 + quad * 8);

    float m_run[2][4], s_run[2][4];
#pragma unroll
    for (int bt = 0; bt < 2; ++bt)
#pragma unroll
        for (int r = 0; r < 4; ++r) { m_run[bt][r] = -INFINITY; s_run[bt][r] = 0.f; }

    const f32x4 zero = {0.f, 0.f, 0.f, 0.f};
    __syncthreads();

    for (int k = 0; k < K_; ++k) {
        const int ck = c * K_ + k;
        const f16x8* Bb = ATf + (size_t)ck * 512;
        f16x8 Bf[4][2];
#pragma unroll
        for (int dt = 0; dt < 4; ++dt)
#pragma unroll
            for (int ks = 0; ks < 2; ++ks)
                Bf[dt][ks] = Bb[(dt * 2 + ks) * 64 + lane];
        float vv[4];
#pragma unroll
        for (int dt = 0; dt < 4; ++dt)
            vv[dt] = v_g[(size_t)ck * D_ + dt * 16 + col];
        const float offk = offs_s[k];

        f32x4 acc[2][4];
#pragma unroll
        for (int bt = 0; bt < 2; ++bt)
#pragma unroll
            for (int dt = 0; dt < 4; ++dt) {
                acc[bt][dt] = __builtin_amdgcn_mfma_f32_16x16x32_f16(
                    Xf[bt][0], Bf[dt][0], zero, 0, 0, 0);
                acc[bt][dt] = __builtin_amdgcn_mfma_f32_16x16x32_f16(
                    Xf[bt][1], Bf[dt][1], acc[bt][dt], 0, 0, 0);
            }

#pragma unroll
        for (int bt = 0; bt < 2; ++bt) {
            float p[4];
#pragma unroll
            for (int r = 0; r < 4; ++r) {
                float s = 0.f;
#pragma unroll
                for (int dt = 0; dt < 4; ++dt) {
                    const float z = acc[bt][dt][r] - vv[dt];
                    s = fmaf(z, z, s);
                }
                p[r] = s;
            }
#pragma unroll
            for (int r = 0; r < 4; ++r) p[r] = sum16(p[r]);
#pragma unroll
            for (int r = 0; r < 4; ++r) {
                const float lp = fmaf(-0.5f, p[r], offk);
                const float nm = fmaxf(m_run[bt][r], lp);
                s_run[bt][r] = s_run[bt][r] * __expf(m_run[bt][r] - nm) + __expf(lp - nm);
                m_run[bt][r] = nm;
            }
        }
    }

    if (col == 0) {
#pragma unroll
        for (int bt = 0; bt < 2; ++bt)
#pragma unroll
            for (int r = 0; r < 4; ++r) {
                const int b = bw + bt * 16 + quad * 4 + r;
                clp_g[(size_t)b * C_ + c] = m_run[bt][r] + __logf(s_run[bt][r]);
            }
    }
}

// ---------------- kernel 3: log_softmax over C per batch row -------------------------
__global__ __launch_bounds__(256) void k_final(const float* __restrict__ clp,
                                               float* __restrict__ out) {
    const int wave = threadIdx.x >> 6;
    const int lane = threadIdx.x & 63;
    const int b = blockIdx.x * 4 + wave;
    const float* row = clp + (size_t)b * C_;
    const float x0 = row[lane];
    const float x1 = (lane < C_ - 64) ? row[64 + lane] : -INFINITY;
    float m = fmaxf(x0, x1);
    for (int o = 32; o > 0; o >>= 1) m = fmaxf(m, __shfl_xor(m, o, 64));
    float s = __expf(x0 - m) + ((lane < C_ - 64) ? __expf(x1 - m) : 0.f);
    for (int o = 32; o > 0; o >>= 1) s += __shfl_xor(s, o, 64);
    const float L = m + __logf(s);
    out[(size_t)b * C_ + lane] = x0 - L;
    if (lane < C_ - 64) out[(size_t)b * C_ + 64 + lane] = x1 - L;
}

extern "C" void kernel_launch(void* const* d_in, const int* in_sizes, int n_in,
                              void* d_out, int out_size, void* d_ws, size_t ws_size,
                              hipStream_t stream) {
    const float* rep = (const float*)d_in[0];        // [B, D]
    const float* ml  = (const float*)d_in[1];        // [C, K]
    const float* loc = (const float*)d_in[2];        // [C, K, D]
    const float* st  = (const float*)d_in[3];        // [C, K, D, D]
    float* out = (float*)d_out;                      // [B, C]

    char* w = (char*)d_ws;
    f16x8*    ATf = (f16x8*)w;                        // 800*512*16 = 6,553,600 B
    _Float16* Xh  = (_Float16*)(w + 6553600);         // 262,144 B
    float*    v   = (float*)(w + 6815744);            // 204,800 B
    float*    ld  = (float*)(w + 7020544);            // 3,200 B
    float*    clp = (float*)(w + 7023744);            // 819,200 B

    k_invert<<<dim3(C_ * K_), dim3(64), 0, stream>>>(st, rep, loc, ATf, Xh, v, ld);
    k_main<<<dim3(B_ / 128, C_), dim3(256), 0, stream>>>(Xh, ATf, v, ml, ld, clp);
    k_final<<<dim3(B_ / 4), dim3(256), 0, stream>>>(clp, out);
}